// Round 7
// baseline (40.742 us; speedup 1.0000x reference)
//
#include <hip/hip_runtime.h>

#define NQ 4
#define NL 4

typedef _Float16 f16x8 __attribute__((ext_vector_type(8)));
typedef float f32x16 __attribute__((ext_vector_type(16)));

#define ITERS 8

// ---------------------------------------------------------------------------
// Fused kernel. Per block:
//   prelude (wave 0): lanes 0-15 push basis columns through the 4-layer SEL
//     unitary -> M[32][16] = [Re V; Im V] in LDS (f32);
//     lanes 32-63 build G[32][16] (FC folded through the PauliZ sign
//     pattern, permuted to match MFMA#1's C-layout; rows 10-31 zero).
//   main loop (identical to R5): per wave-iter 32 samples,
//     MFMA#1 (split-A x2): psi = M . r;  probs -> f16;
//     MFMA#2 (split-A x2): out = G . p (+bias via acc-init);
//     direct predicated float2 stores.
// ---------------------------------------------------------------------------
__global__ __launch_bounds__(256) void qnn_fused(
    const float4* __restrict__ x,     // [B]
    const float*  __restrict__ w,     // [4][4][3]
    const float*  __restrict__ fcw,   // [10][4]
    const float*  __restrict__ fcb,   // [10]
    float*        __restrict__ out,   // [B*10]
    int nB)
{
  __shared__ float sM[512];           // M[32][16]
  __shared__ float sG[512];           // G[32][16]

  int t    = threadIdx.x;
  int lane = t & 63;
  int wv   = t >> 6;
  int col  = lane & 31;
  int hi   = lane >> 5;

  // ---- prelude: build M (lanes 0-15 of wave 0) ----
  if (t < 16) {
    int k = t;
    float pr[16], pi[16];
#pragma unroll
    for (int j = 0; j < 16; ++j) { pr[j] = (j == k) ? 1.f : 0.f; pi[j] = 0.f; }

    const int ranges[4] = {1, 2, 3, 1};
#pragma unroll
    for (int l = 0; l < NL; ++l) {
#pragma unroll
      for (int q = 0; q < NQ; ++q) {
        float phi = w[l*12 + q*3 + 0];
        float th  = w[l*12 + q*3 + 1];
        float om  = w[l*12 + q*3 + 2];
        float st, ct;  __sincosf(0.5f*th, &st, &ct);
        float spo, cpo; __sincosf(0.5f*(phi+om), &spo, &cpo);
        float smo, cmo; __sincosf(0.5f*(phi-om), &smo, &cmo);
        float ar = cpo*ct,  ai = -spo*ct;
        float br = -cmo*st, bi = -smo*st;
        float dr = cmo*st,  di = -smo*st;
        float er = cpo*ct,  ei = spo*ct;
        int m = 8 >> q;
#pragma unroll
        for (int i0 = 0; i0 < 16; ++i0) {
          if (i0 & m) continue;
          int i1 = i0 | m;
          float x0r = pr[i0], x0i = pi[i0], x1r = pr[i1], x1i = pi[i1];
          pr[i0] = ar*x0r - ai*x0i + br*x1r - bi*x1i;
          pi[i0] = ar*x0i + ai*x0r + br*x1i + bi*x1r;
          pr[i1] = dr*x0r - di*x0i + er*x1r - ei*x1i;
          pi[i1] = dr*x0i + di*x0r + er*x1i + ei*x1r;
        }
      }
      int r = ranges[l];
#pragma unroll
      for (int q = 0; q < NQ; ++q) {
        int mc = 8 >> q;
        int mt = 8 >> ((q + r) & 3);
#pragma unroll
        for (int i = 0; i < 16; ++i) {
          if ((i & mc) && !(i & mt)) {
            int i2 = i | mt;
            float tr = pr[i]; pr[i] = pr[i2]; pr[i2] = tr;
            float ti = pi[i]; pi[i] = pi[i2]; pi[i2] = ti;
          }
        }
      }
    }

    int pc = __popc(k) & 3;
#pragma unroll
    for (int j = 0; j < 16; ++j) {
      float re = pr[j], im = pi[j], re2, im2;
      if      (pc == 0) { re2 =  re; im2 =  im; }
      else if (pc == 1) { re2 =  im; im2 = -re; }
      else if (pc == 2) { re2 = -re; im2 = -im; }
      else              { re2 = -im; im2 =  re; }
      sM[j*16 + k]        = re2;
      sM[(16 + j)*16 + k] = im2;
    }
  }

  // ---- prelude: build G (lanes 32-63 of wave 0 handle rows 0-31) ----
  if (t >= 32 && t < 64) {
    int o = t - 32;
#pragma unroll
    for (int kk = 0; kk < 16; ++kk) {
      float g = 0.f;
      if (o < 10) {
        int j = (kk & 3) + 8 * ((kk >> 2) & 1) + 4 * (kk >> 3);
        g = fcw[o*4 + 0] * ((j & 8) ? -1.f : 1.f)
          + fcw[o*4 + 1] * ((j & 4) ? -1.f : 1.f)
          + fcw[o*4 + 2] * ((j & 2) ? -1.f : 1.f)
          + fcw[o*4 + 3] * ((j & 1) ? -1.f : 1.f);
      }
      sG[o*16 + kk] = g;
    }
  }

  __syncthreads();

  // ---- build split-f16 fragments from LDS ----
  int row = col;          // A-fragment row = lane&31
  int k0  = hi * 8;
  f16x8 Ahi, Alo, Ghi, Glo;
#pragma unroll
  for (int i = 0; i < 8; ++i) {
    float v = sM[row * 16 + k0 + i];
    _Float16 h = (_Float16)v;
    Ahi[i] = h;
    Alo[i] = (_Float16)(v - (float)h);
    float g = sG[row * 16 + k0 + i];
    _Float16 gh = (_Float16)g;
    Ghi[i] = gh;
    Glo[i] = (_Float16)(g - (float)gh);
  }

  // bias regs: acc2 rows for this lane: hi=0 -> {0,1,2,3,8,9}, hi=1 -> {4,5,6,7}
  int o0 = hi * 4;
  float b0 = fcb[o0 + 0], b1 = fcb[o0 + 1], b2 = fcb[o0 + 2], b3 = fcb[o0 + 3];
  float b4 = hi ? 0.f : fcb[8];
  float b5 = hi ? 0.f : fcb[9];

  int sbase = blockIdx.x * (ITERS * 128) + wv * 32 + col;

  // prefetch all ITERS x-values (independent loads, all in flight)
  float4 xs[ITERS];
#pragma unroll
  for (int it = 0; it < ITERS; ++it) {
    int s = sbase + it * 128;
    xs[it] = x[(s < nB) ? s : 0];
  }

#pragma unroll
  for (int it = 0; it < ITERS; ++it) {
    int s = sbase + it * 128;
    float4 xv = xs[it];

    // cs0 = hi ? sin(x0/2) : cos(x0/2)
    float cs0 = __sinf(fmaf(0.5f, xv.x, hi ? 0.f : 1.57079632679f));
    float s1, c1, s2, c2, s3, c3;
    __sincosf(0.5f * xv.y, &s1, &c1);
    __sincosf(0.5f * xv.z, &s2, &c2);
    __sincosf(0.5f * xv.w, &s3, &c3);

    float a0 = cs0 * c1, a1 = cs0 * s1;
    float w0 = c2 * c3, w1 = c2 * s3, w2 = s2 * c3, w3 = s2 * s3;
    f16x8 Bf;
    Bf[0] = (_Float16)(a0 * w0); Bf[1] = (_Float16)(a0 * w1);
    Bf[2] = (_Float16)(a0 * w2); Bf[3] = (_Float16)(a0 * w3);
    Bf[4] = (_Float16)(a1 * w0); Bf[5] = (_Float16)(a1 * w1);
    Bf[6] = (_Float16)(a1 * w2); Bf[7] = (_Float16)(a1 * w3);

    f32x16 acc = {0.f,0.f,0.f,0.f,0.f,0.f,0.f,0.f,
                  0.f,0.f,0.f,0.f,0.f,0.f,0.f,0.f};
    acc = __builtin_amdgcn_mfma_f32_32x32x16_f16(Ahi, Bf, acc, 0, 0, 0);
    acc = __builtin_amdgcn_mfma_f32_32x32x16_f16(Alo, Bf, acc, 0, 0, 0);

    // probs: reg jj (re) pairs with reg jj+8 (im)
    f16x8 Bp;
    Bp[0] = (_Float16)fmaf(acc[0], acc[0], acc[8]  * acc[8]);
    Bp[1] = (_Float16)fmaf(acc[1], acc[1], acc[9]  * acc[9]);
    Bp[2] = (_Float16)fmaf(acc[2], acc[2], acc[10] * acc[10]);
    Bp[3] = (_Float16)fmaf(acc[3], acc[3], acc[11] * acc[11]);
    Bp[4] = (_Float16)fmaf(acc[4], acc[4], acc[12] * acc[12]);
    Bp[5] = (_Float16)fmaf(acc[5], acc[5], acc[13] * acc[13]);
    Bp[6] = (_Float16)fmaf(acc[6], acc[6], acc[14] * acc[14]);
    Bp[7] = (_Float16)fmaf(acc[7], acc[7], acc[15] * acc[15]);

    f32x16 acc2 = {b0, b1, b2, b3, b4, b5, 0.f, 0.f,
                   0.f, 0.f, 0.f, 0.f, 0.f, 0.f, 0.f, 0.f};
    acc2 = __builtin_amdgcn_mfma_f32_32x32x16_f16(Ghi, Bp, acc2, 0, 0, 0);
    acc2 = __builtin_amdgcn_mfma_f32_32x32x16_f16(Glo, Bp, acc2, 0, 0, 0);

    if (s < nB) {
      float* op = out + (size_t)s * 10 + o0;   // 8B-aligned
      float2 v01; v01.x = acc2[0]; v01.y = acc2[1];
      float2 v23; v23.x = acc2[2]; v23.y = acc2[3];
      *(float2*)(op + 0) = v01;
      *(float2*)(op + 2) = v23;
      if (!hi) {
        float2 v89; v89.x = acc2[4]; v89.y = acc2[5];
        *(float2*)(out + (size_t)s * 10 + 8) = v89;
      }
    }
  }
}

extern "C" void kernel_launch(void* const* d_in, const int* in_sizes, int n_in,
                              void* d_out, int out_size, void* d_ws, size_t ws_size,
                              hipStream_t stream) {
  const float* x   = (const float*)d_in[0];
  const float* w   = (const float*)d_in[1];
  const float* fcw = (const float*)d_in[2];
  const float* fcb = (const float*)d_in[3];
  float* out = (float*)d_out;
  int nB = in_sizes[0] / 4;

  int nblk = (nB + 128 * ITERS - 1) / (128 * ITERS);
  hipLaunchKernelGGL(qnn_fused, dim3(nblk), dim3(256), 0, stream,
                     (const float4*)x, w, fcw, fcb, out, nB);
}

// Round 8
// 30.211 us; speedup vs baseline: 1.3486x; 1.3486x over previous
//
#include <hip/hip_runtime.h>

#define NQ 4
#define NL 4

typedef _Float16 f16x8 __attribute__((ext_vector_type(8)));
typedef float f32x16 __attribute__((ext_vector_type(16)));

// ---------------------------------------------------------------------------
// Precompute (1 block, 64 thr) — identical to R5 (verified):
//   Mh[32][16] @0, Ml @512, Gh @1024, Gl @1536 (f16 split hi/lo)
// ---------------------------------------------------------------------------
__global__ __launch_bounds__(64) void qnn_precompute(
    const float* __restrict__ w,     // [4][4][3]
    const float* __restrict__ fcw,   // [10][4]
    _Float16* __restrict__ ws)
{
  int k = threadIdx.x;

  if (k < 16) {
    float pr[16], pi[16];
#pragma unroll
    for (int j = 0; j < 16; ++j) { pr[j] = (j == k) ? 1.f : 0.f; pi[j] = 0.f; }

    const int ranges[4] = {1, 2, 3, 1};
#pragma unroll
    for (int l = 0; l < NL; ++l) {
#pragma unroll
      for (int q = 0; q < NQ; ++q) {
        float phi = w[l*12 + q*3 + 0];
        float th  = w[l*12 + q*3 + 1];
        float om  = w[l*12 + q*3 + 2];
        float st, ct;  __sincosf(0.5f*th, &st, &ct);
        float spo, cpo; __sincosf(0.5f*(phi+om), &spo, &cpo);
        float smo, cmo; __sincosf(0.5f*(phi-om), &smo, &cmo);
        float ar = cpo*ct,  ai = -spo*ct;
        float br = -cmo*st, bi = -smo*st;
        float dr = cmo*st,  di = -smo*st;
        float er = cpo*ct,  ei = spo*ct;
        int m = 8 >> q;
#pragma unroll
        for (int i0 = 0; i0 < 16; ++i0) {
          if (i0 & m) continue;
          int i1 = i0 | m;
          float x0r = pr[i0], x0i = pi[i0], x1r = pr[i1], x1i = pi[i1];
          pr[i0] = ar*x0r - ai*x0i + br*x1r - bi*x1i;
          pi[i0] = ar*x0i + ai*x0r + br*x1i + bi*x1r;
          pr[i1] = dr*x0r - di*x0i + er*x1r - ei*x1i;
          pi[i1] = dr*x0i + di*x0r + er*x1i + ei*x1r;
        }
      }
      int r = ranges[l];
#pragma unroll
      for (int q = 0; q < NQ; ++q) {
        int mc = 8 >> q;
        int mt = 8 >> ((q + r) & 3);
#pragma unroll
        for (int i = 0; i < 16; ++i) {
          if ((i & mc) && !(i & mt)) {
            int i2 = i | mt;
            float tr = pr[i]; pr[i] = pr[i2]; pr[i2] = tr;
            float ti = pi[i]; pi[i] = pi[i2]; pi[i2] = ti;
          }
        }
      }
    }

    int pc = __popc(k) & 3;
#pragma unroll
    for (int j = 0; j < 16; ++j) {
      float re = pr[j], im = pi[j], re2, im2;
      if      (pc == 0) { re2 =  re; im2 =  im; }
      else if (pc == 1) { re2 =  im; im2 = -re; }
      else if (pc == 2) { re2 = -re; im2 = -im; }
      else              { re2 = -im; im2 =  re; }
      _Float16 h;
      h = (_Float16)re2;
      ws[j*16 + k]            = h;
      ws[512 + j*16 + k]      = (_Float16)(re2 - (float)h);
      h = (_Float16)im2;
      ws[(16 + j)*16 + k]     = h;
      ws[512 + (16 + j)*16 + k] = (_Float16)(im2 - (float)h);
    }
  }

  if (k < 32) {
#pragma unroll
    for (int kk = 0; kk < 16; ++kk) {
      float g = 0.f;
      if (k < 10) {
        int j = (kk & 3) + 8 * ((kk >> 2) & 1) + 4 * (kk >> 3);
        g = fcw[k*4 + 0] * ((j & 8) ? -1.f : 1.f)
          + fcw[k*4 + 1] * ((j & 4) ? -1.f : 1.f)
          + fcw[k*4 + 2] * ((j & 2) ? -1.f : 1.f)
          + fcw[k*4 + 3] * ((j & 1) ? -1.f : 1.f);
      }
      _Float16 h = (_Float16)g;
      ws[1024 + k*16 + kk] = h;
      ws[1536 + k*16 + kk] = (_Float16)(g - (float)h);
    }
  }
}

// ---------------------------------------------------------------------------
// Main: ONE 32-sample MFMA iteration per wave (no unroll, no register reuse
// over in-flight stores -> no per-iter vmcnt store-ack stall; end-of-wave
// drain is free). Native v_sin/v_cos (input in revolutions; args in
// [0, 0.08] rev -> no range reduction needed).
// ---------------------------------------------------------------------------
#define INV2PI 0.15915494309189535f

__global__ __launch_bounds__(256) void qnn_main(
    const float4* __restrict__ x,     // [B]
    const f16x8*  __restrict__ W8,    // ws: Mh|Ml|Gh|Gl, 64 f16x8 each
    const float*  __restrict__ fcb,   // [10]
    float*        __restrict__ out,   // [B*10]
    int nB)
{
  int t    = threadIdx.x;
  int lane = t & 63;
  int wv   = t >> 6;
  int col  = lane & 31;
  int hi   = lane >> 5;

  int s  = blockIdx.x * 128 + wv * 32 + col;
  int sc = (s < nB) ? s : 0;
  float4 xv = x[sc];                  // issue early

  int fr = (lane & 31) * 2 + hi;
  f16x8 Ahi = W8[fr];
  f16x8 Alo = W8[64 + fr];
  f16x8 Ghi = W8[128 + fr];
  f16x8 Glo = W8[192 + fr];

  // bias: acc2 rows for this lane: hi=0 -> {0,1,2,3,8,9}, hi=1 -> {4,5,6,7}
  int o0 = hi * 4;
  float b0 = fcb[o0 + 0], b1 = fcb[o0 + 1], b2 = fcb[o0 + 2], b3 = fcb[o0 + 3];
  float b4 = hi ? 0.f : fcb[8];
  float b5 = hi ? 0.f : fcb[9];

  // native trig, revolutions: sin(2*pi*(x*INV2PI/2)) = sin(x/2)
  // cs0 = hi ? sin(x0/2) : cos(x0/2) = sin(2pi*(rev0 + (hi?0:1/4)))
  float rev0 = xv.x * (0.5f * INV2PI);
  float cs0  = __builtin_amdgcn_sinf(hi ? rev0 : rev0 + 0.25f);
  float rev1 = xv.y * (0.5f * INV2PI);
  float s1 = __builtin_amdgcn_sinf(rev1), c1 = __builtin_amdgcn_cosf(rev1);
  float rev2 = xv.z * (0.5f * INV2PI);
  float s2 = __builtin_amdgcn_sinf(rev2), c2 = __builtin_amdgcn_cosf(rev2);
  float rev3 = xv.w * (0.5f * INV2PI);
  float s3 = __builtin_amdgcn_sinf(rev3), c3 = __builtin_amdgcn_cosf(rev3);

  float a0 = cs0 * c1, a1 = cs0 * s1;
  float w0 = c2 * c3, w1 = c2 * s3, w2 = s2 * c3, w3 = s2 * s3;
  f16x8 Bf;
  Bf[0] = (_Float16)(a0 * w0); Bf[1] = (_Float16)(a0 * w1);
  Bf[2] = (_Float16)(a0 * w2); Bf[3] = (_Float16)(a0 * w3);
  Bf[4] = (_Float16)(a1 * w0); Bf[5] = (_Float16)(a1 * w1);
  Bf[6] = (_Float16)(a1 * w2); Bf[7] = (_Float16)(a1 * w3);

  f32x16 acc = {0.f,0.f,0.f,0.f,0.f,0.f,0.f,0.f,
                0.f,0.f,0.f,0.f,0.f,0.f,0.f,0.f};
  acc = __builtin_amdgcn_mfma_f32_32x32x16_f16(Ahi, Bf, acc, 0, 0, 0);
  acc = __builtin_amdgcn_mfma_f32_32x32x16_f16(Alo, Bf, acc, 0, 0, 0);

  // probs: reg jj (re) pairs with reg jj+8 (im)
  f16x8 Bp;
  Bp[0] = (_Float16)fmaf(acc[0], acc[0], acc[8]  * acc[8]);
  Bp[1] = (_Float16)fmaf(acc[1], acc[1], acc[9]  * acc[9]);
  Bp[2] = (_Float16)fmaf(acc[2], acc[2], acc[10] * acc[10]);
  Bp[3] = (_Float16)fmaf(acc[3], acc[3], acc[11] * acc[11]);
  Bp[4] = (_Float16)fmaf(acc[4], acc[4], acc[12] * acc[12]);
  Bp[5] = (_Float16)fmaf(acc[5], acc[5], acc[13] * acc[13]);
  Bp[6] = (_Float16)fmaf(acc[6], acc[6], acc[14] * acc[14]);
  Bp[7] = (_Float16)fmaf(acc[7], acc[7], acc[15] * acc[15]);

  f32x16 acc2 = {b0, b1, b2, b3, b4, b5, 0.f, 0.f,
                 0.f, 0.f, 0.f, 0.f, 0.f, 0.f, 0.f, 0.f};
  acc2 = __builtin_amdgcn_mfma_f32_32x32x16_f16(Ghi, Bp, acc2, 0, 0, 0);
  acc2 = __builtin_amdgcn_mfma_f32_32x32x16_f16(Glo, Bp, acc2, 0, 0, 0);

  if (s < nB) {
    float* op = out + (size_t)s * 10 + o0;   // 8B-aligned
    float2 v01; v01.x = acc2[0]; v01.y = acc2[1];
    float2 v23; v23.x = acc2[2]; v23.y = acc2[3];
    *(float2*)(op + 0) = v01;
    *(float2*)(op + 2) = v23;
    if (!hi) {
      float2 v89; v89.x = acc2[4]; v89.y = acc2[5];
      *(float2*)(out + (size_t)s * 10 + 8) = v89;
    }
  }
}

extern "C" void kernel_launch(void* const* d_in, const int* in_sizes, int n_in,
                              void* d_out, int out_size, void* d_ws, size_t ws_size,
                              hipStream_t stream) {
  const float* x   = (const float*)d_in[0];
  const float* w   = (const float*)d_in[1];
  const float* fcw = (const float*)d_in[2];
  const float* fcb = (const float*)d_in[3];
  float* out = (float*)d_out;
  _Float16* ws = (_Float16*)d_ws;   // 2048 f16 = 4 KB
  int nB = in_sizes[0] / 4;

  hipLaunchKernelGGL(qnn_precompute, dim3(1), dim3(64), 0, stream, w, fcw, ws);

  int nblk = (nB + 127) / 128;      // 1 MFMA iteration per wave
  hipLaunchKernelGGL(qnn_main, dim3(nblk), dim3(256), 0, stream,
                     (const float4*)x, (const f16x8*)ws, fcb, out, nB);
}

// Round 10
// 28.920 us; speedup vs baseline: 1.4088x; 1.0446x over previous
//
#include <hip/hip_runtime.h>

#define NQ 4
#define NL 4

typedef _Float16 f16x8 __attribute__((ext_vector_type(8)));
typedef float f32x16 __attribute__((ext_vector_type(16)));

// ---------------------------------------------------------------------------
// Precompute (1 block, 64 thr) — identical to R5-R8 (verified):
//   Mh[32][16] @0, Ml @512, Gh @1024, Gl @1536 (f16 split hi/lo)
// ---------------------------------------------------------------------------
__global__ __launch_bounds__(64) void qnn_precompute(
    const float* __restrict__ w,     // [4][4][3]
    const float* __restrict__ fcw,   // [10][4]
    _Float16* __restrict__ ws)
{
  int k = threadIdx.x;

  if (k < 16) {
    float pr[16], pi[16];
#pragma unroll
    for (int j = 0; j < 16; ++j) { pr[j] = (j == k) ? 1.f : 0.f; pi[j] = 0.f; }

    const int ranges[4] = {1, 2, 3, 1};
#pragma unroll
    for (int l = 0; l < NL; ++l) {
#pragma unroll
      for (int q = 0; q < NQ; ++q) {
        float phi = w[l*12 + q*3 + 0];
        float th  = w[l*12 + q*3 + 1];
        float om  = w[l*12 + q*3 + 2];
        float st, ct;  __sincosf(0.5f*th, &st, &ct);
        float spo, cpo; __sincosf(0.5f*(phi+om), &spo, &cpo);
        float smo, cmo; __sincosf(0.5f*(phi-om), &smo, &cmo);
        float ar = cpo*ct,  ai = -spo*ct;
        float br = -cmo*st, bi = -smo*st;
        float dr = cmo*st,  di = -smo*st;
        float er = cpo*ct,  ei = spo*ct;
        int m = 8 >> q;
#pragma unroll
        for (int i0 = 0; i0 < 16; ++i0) {
          if (i0 & m) continue;
          int i1 = i0 | m;
          float x0r = pr[i0], x0i = pi[i0], x1r = pr[i1], x1i = pi[i1];
          pr[i0] = ar*x0r - ai*x0i + br*x1r - bi*x1i;
          pi[i0] = ar*x0i + ai*x0r + br*x1i + bi*x1r;
          pr[i1] = dr*x0r - di*x0i + er*x1r - ei*x1i;
          pi[i1] = dr*x0i + di*x0r + er*x1i + ei*x1r;
        }
      }
      int r = ranges[l];
#pragma unroll
      for (int q = 0; q < NQ; ++q) {
        int mc = 8 >> q;
        int mt = 8 >> ((q + r) & 3);
#pragma unroll
        for (int i = 0; i < 16; ++i) {
          if ((i & mc) && !(i & mt)) {
            int i2 = i | mt;
            float tr = pr[i]; pr[i] = pr[i2]; pr[i2] = tr;
            float ti = pi[i]; pi[i] = pi[i2]; pi[i2] = ti;
          }
        }
      }
    }

    int pc = __popc(k) & 3;
#pragma unroll
    for (int j = 0; j < 16; ++j) {
      float re = pr[j], im = pi[j], re2, im2;
      if      (pc == 0) { re2 =  re; im2 =  im; }
      else if (pc == 1) { re2 =  im; im2 = -re; }
      else if (pc == 2) { re2 = -re; im2 = -im; }
      else              { re2 = -im; im2 =  re; }
      _Float16 h;
      h = (_Float16)re2;
      ws[j*16 + k]            = h;
      ws[512 + j*16 + k]      = (_Float16)(re2 - (float)h);
      h = (_Float16)im2;
      ws[(16 + j)*16 + k]     = h;
      ws[512 + (16 + j)*16 + k] = (_Float16)(im2 - (float)h);
    }
  }

  if (k < 32) {
#pragma unroll
    for (int kk = 0; kk < 16; ++kk) {
      float g = 0.f;
      if (k < 10) {
        int j = (kk & 3) + 8 * ((kk >> 2) & 1) + 4 * (kk >> 3);
        g = fcw[k*4 + 0] * ((j & 8) ? -1.f : 1.f)
          + fcw[k*4 + 1] * ((j & 4) ? -1.f : 1.f)
          + fcw[k*4 + 2] * ((j & 2) ? -1.f : 1.f)
          + fcw[k*4 + 3] * ((j & 1) ? -1.f : 1.f);
      }
      _Float16 h = (_Float16)g;
      ws[1024 + k*16 + kk] = h;
      ws[1536 + k*16 + kk] = (_Float16)(g - (float)h);
    }
  }
}

#define INV2PI 0.15915494309189535f
#define CHUNKS 4
#define CSAMP  256          // samples per chunk (= block size)

// ---------------------------------------------------------------------------
// Main: block-level streaming pipeline.
// Per chunk of 256 samples:
//   - issue next chunk's 256 x-loads early (value lands in VGPR during
//     compute; ds_write into xbuf after compute = T14 issue-early/write-late)
//   - compute 2 MFMA groups per wave from LDS xbuf (math identical to R7)
//   - stage results in LDS obuf, then bulk fully-coalesced dwordx4 stores
//     (3 guarded stores per thread: 640 dwordx4 with 256 threads — R8's bug)
// ---------------------------------------------------------------------------
__global__ __launch_bounds__(256) void qnn_main(
    const float4* __restrict__ x,     // [B]
    const f16x8*  __restrict__ W8,    // ws: Mh|Ml|Gh|Gl, 64 f16x8 each
    const float*  __restrict__ fcb,   // [10]
    float*        __restrict__ out,   // [B*10]
    int nB)
{
  __shared__ float4 xbuf[2][CSAMP];        // 8 KB double-buffered input
  __shared__ float  obuf[CSAMP * 10];      // 10 KB output staging

  int t    = threadIdx.x;
  int lane = t & 63;
  int wv   = t >> 6;
  int col  = lane & 31;
  int hi   = lane >> 5;

  int fr = col * 2 + hi;
  f16x8 Ahi = W8[fr];
  f16x8 Alo = W8[64 + fr];
  f16x8 Ghi = W8[128 + fr];
  f16x8 Glo = W8[192 + fr];

  // bias: acc2 rows for this lane: hi=0 -> {0,1,2,3,8,9}, hi=1 -> {4,5,6,7}
  int o0 = hi * 4;
  float b0 = fcb[o0 + 0], b1 = fcb[o0 + 1], b2 = fcb[o0 + 2], b3 = fcb[o0 + 3];
  float b4 = hi ? 0.f : fcb[8];
  float b5 = hi ? 0.f : fcb[9];

  int base = blockIdx.x * (CHUNKS * CSAMP);
  int lim  = nB * 10;

  // prologue: load chunk 0 into xbuf[0]
  {
    int s = base + t;
    float4 pv = x[(s < nB) ? s : (nB - 1)];
    xbuf[0][t] = pv;
  }
  __syncthreads();

#pragma unroll
  for (int c = 0; c < CHUNKS; ++c) {
    // issue next chunk's load early (lands during compute)
    float4 nv;
    if (c + 1 < CHUNKS) {
      int s = base + (c + 1) * CSAMP + t;
      nv = x[(s < nB) ? s : (nB - 1)];
    }

    // compute 2 MFMA groups (64 samples per wave)
#pragma unroll
    for (int g = 0; g < 2; ++g) {
      int sl = wv * 64 + g * 32 + col;     // sample index within chunk
      float4 xv = xbuf[c & 1][sl];         // broadcast pair read

      float rev0 = xv.x * (0.5f * INV2PI);
      float cs0  = __builtin_amdgcn_sinf(hi ? rev0 : rev0 + 0.25f);
      float rev1 = xv.y * (0.5f * INV2PI);
      float s1 = __builtin_amdgcn_sinf(rev1), c1 = __builtin_amdgcn_cosf(rev1);
      float rev2 = xv.z * (0.5f * INV2PI);
      float s2 = __builtin_amdgcn_sinf(rev2), c2 = __builtin_amdgcn_cosf(rev2);
      float rev3 = xv.w * (0.5f * INV2PI);
      float s3 = __builtin_amdgcn_sinf(rev3), c3 = __builtin_amdgcn_cosf(rev3);

      float a0 = cs0 * c1, a1 = cs0 * s1;
      float w0 = c2 * c3, w1 = c2 * s3, w2 = s2 * c3, w3 = s2 * s3;
      f16x8 Bf;
      Bf[0] = (_Float16)(a0 * w0); Bf[1] = (_Float16)(a0 * w1);
      Bf[2] = (_Float16)(a0 * w2); Bf[3] = (_Float16)(a0 * w3);
      Bf[4] = (_Float16)(a1 * w0); Bf[5] = (_Float16)(a1 * w1);
      Bf[6] = (_Float16)(a1 * w2); Bf[7] = (_Float16)(a1 * w3);

      f32x16 acc = {0.f,0.f,0.f,0.f,0.f,0.f,0.f,0.f,
                    0.f,0.f,0.f,0.f,0.f,0.f,0.f,0.f};
      acc = __builtin_amdgcn_mfma_f32_32x32x16_f16(Ahi, Bf, acc, 0, 0, 0);
      acc = __builtin_amdgcn_mfma_f32_32x32x16_f16(Alo, Bf, acc, 0, 0, 0);

      f16x8 Bp;
      Bp[0] = (_Float16)fmaf(acc[0], acc[0], acc[8]  * acc[8]);
      Bp[1] = (_Float16)fmaf(acc[1], acc[1], acc[9]  * acc[9]);
      Bp[2] = (_Float16)fmaf(acc[2], acc[2], acc[10] * acc[10]);
      Bp[3] = (_Float16)fmaf(acc[3], acc[3], acc[11] * acc[11]);
      Bp[4] = (_Float16)fmaf(acc[4], acc[4], acc[12] * acc[12]);
      Bp[5] = (_Float16)fmaf(acc[5], acc[5], acc[13] * acc[13]);
      Bp[6] = (_Float16)fmaf(acc[6], acc[6], acc[14] * acc[14]);
      Bp[7] = (_Float16)fmaf(acc[7], acc[7], acc[15] * acc[15]);

      f32x16 acc2 = {b0, b1, b2, b3, b4, b5, 0.f, 0.f,
                     0.f, 0.f, 0.f, 0.f, 0.f, 0.f, 0.f, 0.f};
      acc2 = __builtin_amdgcn_mfma_f32_32x32x16_f16(Ghi, Bp, acc2, 0, 0, 0);
      acc2 = __builtin_amdgcn_mfma_f32_32x32x16_f16(Glo, Bp, acc2, 0, 0, 0);

      // stage into obuf (LDS)
      float2 v01; v01.x = acc2[0]; v01.y = acc2[1];
      float2 v23; v23.x = acc2[2]; v23.y = acc2[3];
      *(float2*)&obuf[sl * 10 + o0]     = v01;
      *(float2*)&obuf[sl * 10 + o0 + 2] = v23;
      if (!hi) {
        float2 v89; v89.x = acc2[4]; v89.y = acc2[5];
        *(float2*)&obuf[sl * 10 + 8] = v89;
      }
    }

    // write-late: next chunk into the other xbuf half
    if (c + 1 < CHUNKS) {
      xbuf[(c + 1) & 1][t] = nv;
    }
    __syncthreads();     // obuf complete + xbuf[c+1] landed

    // bulk coalesced store: 2560 floats = 640 dwordx4, 256 threads x 3
    int cb = base * 10 + c * (CSAMP * 10);
#pragma unroll
    for (int i = 0; i < 3; ++i) {
      int idx = t + i * 256;
      if (idx < 640) {
        int gidx = cb + idx * 4;
        if (gidx < lim) {
          float4 v = *(float4*)&obuf[idx * 4];
          *(float4*)&out[gidx] = v;
        }
      }
    }
    __syncthreads();     // obuf reusable
  }
}

extern "C" void kernel_launch(void* const* d_in, const int* in_sizes, int n_in,
                              void* d_out, int out_size, void* d_ws, size_t ws_size,
                              hipStream_t stream) {
  const float* x   = (const float*)d_in[0];
  const float* w   = (const float*)d_in[1];
  const float* fcw = (const float*)d_in[2];
  const float* fcb = (const float*)d_in[3];
  float* out = (float*)d_out;
  _Float16* ws = (_Float16*)d_ws;   // 2048 f16 = 4 KB
  int nB = in_sizes[0] / 4;

  hipLaunchKernelGGL(qnn_precompute, dim3(1), dim3(64), 0, stream, w, fcw, ws);

  int nblk = (nB + CHUNKS * CSAMP - 1) / (CHUNKS * CSAMP);
  hipLaunchKernelGGL(qnn_main, dim3(nblk), dim3(256), 0, stream,
                     (const float4*)x, (const f16x8*)ws, fcb, out, nB);
}

// Round 11
// 22.219 us; speedup vs baseline: 1.8337x; 1.3016x over previous
//
#include <hip/hip_runtime.h>

#define NQ 4
#define NL 4

typedef _Float16 f16x8 __attribute__((ext_vector_type(8)));
typedef float f32x16 __attribute__((ext_vector_type(16)));

#define INV2PI 0.15915494309189535f
#define CHUNKS 4
#define CSAMP  256          // samples per chunk (= block size)

// ---------------------------------------------------------------------------
// Single fused kernel.
// Parallel prelude (all 256 threads, ~600 cyc): thread (k = t>>4, j = t&15)
// owns state entry psi_k[j]. Rot gates via __shfl_xor pair exchange
// (+8 FMA + coeff selects); per-layer CNOT ring composed into one lane
// permutation (4 bit-ops + one __shfl). Fold (-i)^popc(k), write
// M[32][16] / G[32][16] to LDS, build split-f16 MFMA fragments.
// Main loop: byte-identical to R9's streaming pipeline (verified).
// ---------------------------------------------------------------------------
__global__ __launch_bounds__(256) void qnn_fused(
    const float4* __restrict__ x,     // [B]
    const float*  __restrict__ w,     // [4][4][3]
    const float*  __restrict__ fcw,   // [10][4]
    const float*  __restrict__ fcb,   // [10]
    float*        __restrict__ out,   // [B*10]
    int nB)
{
  __shared__ float  sM[512];               // M[32][16]
  __shared__ float  sG[512];               // G[32][16]
  __shared__ float4 xbuf[2][CSAMP];        // 8 KB double-buffered input
  __shared__ float  obuf[CSAMP * 10];      // 10 KB output staging

  int t    = threadIdx.x;
  int lane = t & 63;
  int wv   = t >> 6;
  int col  = lane & 31;
  int hi   = lane >> 5;

  // ================= parallel prelude =================
  {
    int k = t >> 4;        // basis column 0..15
    int j = t & 15;        // state row 0..15
    int gbase = lane & 48; // lane group base for shfl

    float re = (j == k) ? 1.f : 0.f;
    float im = 0.f;

    const int ranges[4] = {1, 2, 3, 1};
#pragma unroll
    for (int l = 0; l < NL; ++l) {
      // 4 Rot gates
#pragma unroll
      for (int q = 0; q < NQ; ++q) {
        float phi = w[l*12 + q*3 + 0];
        float th  = w[l*12 + q*3 + 1];
        float om  = w[l*12 + q*3 + 2];
        float st, ct;  __sincosf(0.5f*th, &st, &ct);
        float spo, cpo; __sincosf(0.5f*(phi+om), &spo, &cpo);
        float smo, cmo; __sincosf(0.5f*(phi-om), &smo, &cmo);
        // a = cpo*ct - i spo*ct ; b = -cmo*st - i smo*st
        // d = cmo*st - i smo*st ; e = cpo*ct + i spo*ct
        float ar = cpo*ct,  ai = -spo*ct;
        float br = -cmo*st, bi = -smo*st;
        float dr = cmo*st,  di = -smo*st;
        float er = cpo*ct,  ei = spo*ct;

        int m = 8 >> q;
        float pre = __shfl_xor(re, m);
        float pim = __shfl_xor(im, m);
        bool one = (j & m) != 0;
        float scr = one ? er : ar, sci = one ? ei : ai;   // self coeff
        float pcr = one ? dr : br, pci = one ? di : bi;   // partner coeff
        float nre = scr*re - sci*im + pcr*pre - pci*pim;
        float nim = scr*im + sci*re + pcr*pim + pci*pre;
        re = nre; im = nim;
      }
      // CNOT ring composed: src = g0(g1(g2(g3(j))))
      int r = ranges[l];
      int src = j;
#pragma unroll
      for (int q = 3; q >= 0; --q) {
        int mc = 8 >> q;
        int mt = 8 >> ((q + r) & 3);
        src ^= (src & mc) ? mt : 0;
      }
      re = __shfl(re, gbase + src);
      im = __shfl(im, gbase + src);
    }

    // fold (-i)^popcount(k)
    int pc = __popc(k) & 3;
    float re2, im2;
    if      (pc == 0) { re2 =  re; im2 =  im; }
    else if (pc == 1) { re2 =  im; im2 = -re; }
    else if (pc == 2) { re2 = -re; im2 = -im; }
    else              { re2 = -im; im2 =  re; }
    sM[j*16 + k]        = re2;
    sM[(16 + j)*16 + k] = im2;

    // G: rows 0-9 = FC folded through PauliZ signs (permuted); rows 10-31 = 0
    if (t < 160) {
      int o  = t >> 4;
      int kk = t & 15;
      int jj = (kk & 3) + 8 * ((kk >> 2) & 1) + 4 * (kk >> 3);
      float g = fcw[o*4 + 0] * ((jj & 8) ? -1.f : 1.f)
              + fcw[o*4 + 1] * ((jj & 4) ? -1.f : 1.f)
              + fcw[o*4 + 2] * ((jj & 2) ? -1.f : 1.f)
              + fcw[o*4 + 3] * ((jj & 1) ? -1.f : 1.f);
      sG[t] = g;
    }
    for (int i = t; i < 352; i += 256) sG[160 + i] = 0.f;
  }
  __syncthreads();

  // ---- build split-f16 fragments from LDS ----
  int row = col;
  int k0  = hi * 8;
  f16x8 Ahi, Alo, Ghi, Glo;
#pragma unroll
  for (int i = 0; i < 8; ++i) {
    float v = sM[row * 16 + k0 + i];
    _Float16 h = (_Float16)v;
    Ahi[i] = h;
    Alo[i] = (_Float16)(v - (float)h);
    float g = sG[row * 16 + k0 + i];
    _Float16 gh = (_Float16)g;
    Ghi[i] = gh;
    Glo[i] = (_Float16)(g - (float)gh);
  }

  // bias: acc2 rows for this lane: hi=0 -> {0,1,2,3,8,9}, hi=1 -> {4,5,6,7}
  int o0 = hi * 4;
  float b0 = fcb[o0 + 0], b1 = fcb[o0 + 1], b2 = fcb[o0 + 2], b3 = fcb[o0 + 3];
  float b4 = hi ? 0.f : fcb[8];
  float b5 = hi ? 0.f : fcb[9];

  int base = blockIdx.x * (CHUNKS * CSAMP);
  int lim  = nB * 10;

  // prologue: load chunk 0 into xbuf[0]
  {
    int s = base + t;
    float4 pv = x[(s < nB) ? s : (nB - 1)];
    xbuf[0][t] = pv;
  }
  __syncthreads();

#pragma unroll
  for (int c = 0; c < CHUNKS; ++c) {
    // issue next chunk's load early (lands during compute)
    float4 nv;
    if (c + 1 < CHUNKS) {
      int s = base + (c + 1) * CSAMP + t;
      nv = x[(s < nB) ? s : (nB - 1)];
    }

    // compute 2 MFMA groups (64 samples per wave)
#pragma unroll
    for (int g = 0; g < 2; ++g) {
      int sl = wv * 64 + g * 32 + col;
      float4 xv = xbuf[c & 1][sl];

      float rev0 = xv.x * (0.5f * INV2PI);
      float cs0  = __builtin_amdgcn_sinf(hi ? rev0 : rev0 + 0.25f);
      float rev1 = xv.y * (0.5f * INV2PI);
      float s1 = __builtin_amdgcn_sinf(rev1), c1 = __builtin_amdgcn_cosf(rev1);
      float rev2 = xv.z * (0.5f * INV2PI);
      float s2 = __builtin_amdgcn_sinf(rev2), c2 = __builtin_amdgcn_cosf(rev2);
      float rev3 = xv.w * (0.5f * INV2PI);
      float s3 = __builtin_amdgcn_sinf(rev3), c3 = __builtin_amdgcn_cosf(rev3);

      float a0 = cs0 * c1, a1 = cs0 * s1;
      float w0 = c2 * c3, w1 = c2 * s3, w2 = s2 * c3, w3 = s2 * s3;
      f16x8 Bf;
      Bf[0] = (_Float16)(a0 * w0); Bf[1] = (_Float16)(a0 * w1);
      Bf[2] = (_Float16)(a0 * w2); Bf[3] = (_Float16)(a0 * w3);
      Bf[4] = (_Float16)(a1 * w0); Bf[5] = (_Float16)(a1 * w1);
      Bf[6] = (_Float16)(a1 * w2); Bf[7] = (_Float16)(a1 * w3);

      f32x16 acc = {0.f,0.f,0.f,0.f,0.f,0.f,0.f,0.f,
                    0.f,0.f,0.f,0.f,0.f,0.f,0.f,0.f};
      acc = __builtin_amdgcn_mfma_f32_32x32x16_f16(Ahi, Bf, acc, 0, 0, 0);
      acc = __builtin_amdgcn_mfma_f32_32x32x16_f16(Alo, Bf, acc, 0, 0, 0);

      f16x8 Bp;
      Bp[0] = (_Float16)fmaf(acc[0], acc[0], acc[8]  * acc[8]);
      Bp[1] = (_Float16)fmaf(acc[1], acc[1], acc[9]  * acc[9]);
      Bp[2] = (_Float16)fmaf(acc[2], acc[2], acc[10] * acc[10]);
      Bp[3] = (_Float16)fmaf(acc[3], acc[3], acc[11] * acc[11]);
      Bp[4] = (_Float16)fmaf(acc[4], acc[4], acc[12] * acc[12]);
      Bp[5] = (_Float16)fmaf(acc[5], acc[5], acc[13] * acc[13]);
      Bp[6] = (_Float16)fmaf(acc[6], acc[6], acc[14] * acc[14]);
      Bp[7] = (_Float16)fmaf(acc[7], acc[7], acc[15] * acc[15]);

      f32x16 acc2 = {b0, b1, b2, b3, b4, b5, 0.f, 0.f,
                     0.f, 0.f, 0.f, 0.f, 0.f, 0.f, 0.f, 0.f};
      acc2 = __builtin_amdgcn_mfma_f32_32x32x16_f16(Ghi, Bp, acc2, 0, 0, 0);
      acc2 = __builtin_amdgcn_mfma_f32_32x32x16_f16(Glo, Bp, acc2, 0, 0, 0);

      float2 v01; v01.x = acc2[0]; v01.y = acc2[1];
      float2 v23; v23.x = acc2[2]; v23.y = acc2[3];
      *(float2*)&obuf[sl * 10 + o0]     = v01;
      *(float2*)&obuf[sl * 10 + o0 + 2] = v23;
      if (!hi) {
        float2 v89; v89.x = acc2[4]; v89.y = acc2[5];
        *(float2*)&obuf[sl * 10 + 8] = v89;
      }
    }

    // write-late: next chunk into the other xbuf half
    if (c + 1 < CHUNKS) {
      xbuf[(c + 1) & 1][t] = nv;
    }
    __syncthreads();     // obuf complete + xbuf[c+1] landed

    // bulk coalesced store: 2560 floats = 640 dwordx4, 256 threads x 3
    int cb = base * 10 + c * (CSAMP * 10);
#pragma unroll
    for (int i = 0; i < 3; ++i) {
      int idx = t + i * 256;
      if (idx < 640) {
        int gidx = cb + idx * 4;
        if (gidx < lim) {
          float4 v = *(float4*)&obuf[idx * 4];
          *(float4*)&out[gidx] = v;
        }
      }
    }
    __syncthreads();     // obuf reusable
  }
}

extern "C" void kernel_launch(void* const* d_in, const int* in_sizes, int n_in,
                              void* d_out, int out_size, void* d_ws, size_t ws_size,
                              hipStream_t stream) {
  const float* x   = (const float*)d_in[0];
  const float* w   = (const float*)d_in[1];
  const float* fcw = (const float*)d_in[2];
  const float* fcb = (const float*)d_in[3];
  float* out = (float*)d_out;
  int nB = in_sizes[0] / 4;

  int nblk = (nB + CHUNKS * CSAMP - 1) / (CHUNKS * CSAMP);
  hipLaunchKernelGGL(qnn_fused, dim3(nblk), dim3(256), 0, stream,
                     (const float4*)x, w, fcw, fcb, out, nB);
}

// Round 12
// 21.222 us; speedup vs baseline: 1.9198x; 1.0470x over previous
//
#include <hip/hip_runtime.h>

#define NQ 4
#define NL 4

typedef _Float16 f16x8 __attribute__((ext_vector_type(8)));
typedef float f32x16 __attribute__((ext_vector_type(16)));

#define INV2PI 0.15915494309189535f
#define CHUNKS 4
#define CSAMP  256          // samples per chunk (= block size)

// ---------------------------------------------------------------------------
// Single fused kernel (R10 structure + barrier-halving + Glo drop).
// Parallel prelude: thread (k=t>>4, j=t&15) owns psi_k[j]; Rot gates via
// __shfl_xor pair exchange; per-layer CNOT ring = one composed lane perm.
// Main loop per chunk: compute 2 MFMA groups -> obuf[c&1]; ONE barrier;
// bulk dwordx4 stores overlap next chunk's compute (obuf double-buffered).
// MFMA#1 split-f16 (Ahi/Alo); MFMA#2 plain-f16 G (error <= 1.5e-3).
// ---------------------------------------------------------------------------
__global__ __launch_bounds__(256) void qnn_fused(
    const float4* __restrict__ x,     // [B]
    const float*  __restrict__ w,     // [4][4][3]
    const float*  __restrict__ fcw,   // [10][4]
    const float*  __restrict__ fcb,   // [10]
    float*        __restrict__ out,   // [B*10]
    int nB)
{
  __shared__ float  sM[512];               // M[32][16]
  __shared__ float  sG[512];               // G[32][16]
  __shared__ float4 xbuf[2][CSAMP];        // 8 KB double-buffered input
  __shared__ float  obuf[2][CSAMP * 10];   // 20 KB double-buffered output

  int t    = threadIdx.x;
  int lane = t & 63;
  int wv   = t >> 6;
  int col  = lane & 31;
  int hi   = lane >> 5;

  // ================= parallel prelude =================
  {
    int k = t >> 4;        // basis column 0..15
    int j = t & 15;        // state row 0..15
    int gbase = lane & 48; // lane group base for shfl

    float re = (j == k) ? 1.f : 0.f;
    float im = 0.f;

    const int ranges[4] = {1, 2, 3, 1};
#pragma unroll
    for (int l = 0; l < NL; ++l) {
#pragma unroll
      for (int q = 0; q < NQ; ++q) {
        float phi = w[l*12 + q*3 + 0];
        float th  = w[l*12 + q*3 + 1];
        float om  = w[l*12 + q*3 + 2];
        float st, ct;  __sincosf(0.5f*th, &st, &ct);
        float spo, cpo; __sincosf(0.5f*(phi+om), &spo, &cpo);
        float smo, cmo; __sincosf(0.5f*(phi-om), &smo, &cmo);
        float ar = cpo*ct,  ai = -spo*ct;
        float br = -cmo*st, bi = -smo*st;
        float dr = cmo*st,  di = -smo*st;
        float er = cpo*ct,  ei = spo*ct;

        int m = 8 >> q;
        float pre = __shfl_xor(re, m);
        float pim = __shfl_xor(im, m);
        bool one = (j & m) != 0;
        float scr = one ? er : ar, sci = one ? ei : ai;
        float pcr = one ? dr : br, pci = one ? di : bi;
        float nre = scr*re - sci*im + pcr*pre - pci*pim;
        float nim = scr*im + sci*re + pcr*pim + pci*pre;
        re = nre; im = nim;
      }
      int r = ranges[l];
      int src = j;
#pragma unroll
      for (int q = 3; q >= 0; --q) {
        int mc = 8 >> q;
        int mt = 8 >> ((q + r) & 3);
        src ^= (src & mc) ? mt : 0;
      }
      re = __shfl(re, gbase + src);
      im = __shfl(im, gbase + src);
    }

    int pc = __popc(k) & 3;
    float re2, im2;
    if      (pc == 0) { re2 =  re; im2 =  im; }
    else if (pc == 1) { re2 =  im; im2 = -re; }
    else if (pc == 2) { re2 = -re; im2 = -im; }
    else              { re2 = -im; im2 =  re; }
    sM[j*16 + k]        = re2;
    sM[(16 + j)*16 + k] = im2;

    if (t < 160) {
      int o  = t >> 4;
      int kk = t & 15;
      int jj = (kk & 3) + 8 * ((kk >> 2) & 1) + 4 * (kk >> 3);
      float g = fcw[o*4 + 0] * ((jj & 8) ? -1.f : 1.f)
              + fcw[o*4 + 1] * ((jj & 4) ? -1.f : 1.f)
              + fcw[o*4 + 2] * ((jj & 2) ? -1.f : 1.f)
              + fcw[o*4 + 3] * ((jj & 1) ? -1.f : 1.f);
      sG[t] = g;
    }
    for (int i = t; i < 352; i += 256) sG[160 + i] = 0.f;
  }
  __syncthreads();

  // ---- build fragments from LDS (split-f16 M, plain-f16 G) ----
  int row = col;
  int k0  = hi * 8;
  f16x8 Ahi, Alo, Ghi;
#pragma unroll
  for (int i = 0; i < 8; ++i) {
    float v = sM[row * 16 + k0 + i];
    _Float16 h = (_Float16)v;
    Ahi[i] = h;
    Alo[i] = (_Float16)(v - (float)h);
    Ghi[i] = (_Float16)sG[row * 16 + k0 + i];
  }

  // bias: acc2 rows for this lane: hi=0 -> {0,1,2,3,8,9}, hi=1 -> {4,5,6,7}
  int o0 = hi * 4;
  float b0 = fcb[o0 + 0], b1 = fcb[o0 + 1], b2 = fcb[o0 + 2], b3 = fcb[o0 + 3];
  float b4 = hi ? 0.f : fcb[8];
  float b5 = hi ? 0.f : fcb[9];

  int base = blockIdx.x * (CHUNKS * CSAMP);
  int lim  = nB * 10;

  // prologue: load chunk 0 into xbuf[0]
  {
    int s = base + t;
    float4 pv = x[(s < nB) ? s : (nB - 1)];
    xbuf[0][t] = pv;
  }
  __syncthreads();

#pragma unroll
  for (int c = 0; c < CHUNKS; ++c) {
    // issue next chunk's load early (lands during compute)
    float4 nv;
    if (c + 1 < CHUNKS) {
      int s = base + (c + 1) * CSAMP + t;
      nv = x[(s < nB) ? s : (nB - 1)];
    }

    float* ob = obuf[c & 1];

    // compute 2 MFMA groups (64 samples per wave)
#pragma unroll
    for (int g = 0; g < 2; ++g) {
      int sl = wv * 64 + g * 32 + col;
      float4 xv = xbuf[c & 1][sl];

      float rev0 = xv.x * (0.5f * INV2PI);
      float cs0  = __builtin_amdgcn_sinf(hi ? rev0 : rev0 + 0.25f);
      float rev1 = xv.y * (0.5f * INV2PI);
      float s1 = __builtin_amdgcn_sinf(rev1), c1 = __builtin_amdgcn_cosf(rev1);
      float rev2 = xv.z * (0.5f * INV2PI);
      float s2 = __builtin_amdgcn_sinf(rev2), c2 = __builtin_amdgcn_cosf(rev2);
      float rev3 = xv.w * (0.5f * INV2PI);
      float s3 = __builtin_amdgcn_sinf(rev3), c3 = __builtin_amdgcn_cosf(rev3);

      float a0 = cs0 * c1, a1 = cs0 * s1;
      float w0 = c2 * c3, w1 = c2 * s3, w2 = s2 * c3, w3 = s2 * s3;
      f16x8 Bf;
      Bf[0] = (_Float16)(a0 * w0); Bf[1] = (_Float16)(a0 * w1);
      Bf[2] = (_Float16)(a0 * w2); Bf[3] = (_Float16)(a0 * w3);
      Bf[4] = (_Float16)(a1 * w0); Bf[5] = (_Float16)(a1 * w1);
      Bf[6] = (_Float16)(a1 * w2); Bf[7] = (_Float16)(a1 * w3);

      f32x16 acc = {0.f,0.f,0.f,0.f,0.f,0.f,0.f,0.f,
                    0.f,0.f,0.f,0.f,0.f,0.f,0.f,0.f};
      acc = __builtin_amdgcn_mfma_f32_32x32x16_f16(Ahi, Bf, acc, 0, 0, 0);
      acc = __builtin_amdgcn_mfma_f32_32x32x16_f16(Alo, Bf, acc, 0, 0, 0);

      f16x8 Bp;
      Bp[0] = (_Float16)fmaf(acc[0], acc[0], acc[8]  * acc[8]);
      Bp[1] = (_Float16)fmaf(acc[1], acc[1], acc[9]  * acc[9]);
      Bp[2] = (_Float16)fmaf(acc[2], acc[2], acc[10] * acc[10]);
      Bp[3] = (_Float16)fmaf(acc[3], acc[3], acc[11] * acc[11]);
      Bp[4] = (_Float16)fmaf(acc[4], acc[4], acc[12] * acc[12]);
      Bp[5] = (_Float16)fmaf(acc[5], acc[5], acc[13] * acc[13]);
      Bp[6] = (_Float16)fmaf(acc[6], acc[6], acc[14] * acc[14]);
      Bp[7] = (_Float16)fmaf(acc[7], acc[7], acc[15] * acc[15]);

      f32x16 acc2 = {b0, b1, b2, b3, b4, b5, 0.f, 0.f,
                     0.f, 0.f, 0.f, 0.f, 0.f, 0.f, 0.f, 0.f};
      acc2 = __builtin_amdgcn_mfma_f32_32x32x16_f16(Ghi, Bp, acc2, 0, 0, 0);

      float2 v01; v01.x = acc2[0]; v01.y = acc2[1];
      float2 v23; v23.x = acc2[2]; v23.y = acc2[3];
      *(float2*)&ob[sl * 10 + o0]     = v01;
      *(float2*)&ob[sl * 10 + o0 + 2] = v23;
      if (!hi) {
        float2 v89; v89.x = acc2[4]; v89.y = acc2[5];
        *(float2*)&ob[sl * 10 + 8] = v89;
      }
    }

    // write-late: next chunk into the other xbuf half
    if (c + 1 < CHUNKS) {
      xbuf[(c + 1) & 1][t] = nv;
    }
    __syncthreads();   // obuf[c&1] complete + xbuf[c+1] landed
                       // (obuf[c&1] is next overwritten at c+2, after the
                       //  c+1 barrier has drained all waves' ds_reads)

    // bulk coalesced store: 2560 floats = 640 dwordx4, 256 threads x 3
    int cb = base * 10 + c * (CSAMP * 10);
#pragma unroll
    for (int i = 0; i < 3; ++i) {
      int idx = t + i * 256;
      if (idx < 640) {
        int gidx = cb + idx * 4;
        if (gidx < lim) {
          float4 v = *(float4*)&ob[idx * 4];
          *(float4*)&out[gidx] = v;
        }
      }
    }
  }
}

extern "C" void kernel_launch(void* const* d_in, const int* in_sizes, int n_in,
                              void* d_out, int out_size, void* d_ws, size_t ws_size,
                              hipStream_t stream) {
  const float* x   = (const float*)d_in[0];
  const float* w   = (const float*)d_in[1];
  const float* fcw = (const float*)d_in[2];
  const float* fcb = (const float*)d_in[3];
  float* out = (float*)d_out;
  int nB = in_sizes[0] / 4;

  int nblk = (nB + CHUNKS * CSAMP - 1) / (CHUNKS * CSAMP);
  hipLaunchKernelGGL(qnn_fused, dim3(nblk), dim3(256), 0, stream,
                     (const float4*)x, w, fcw, fcb, out, nB);
}